// Round 7
// baseline (250.317 us; speedup 1.0000x reference)
//
#include <hip/hip_runtime.h>

#define B_ 32
#define Q_ 16
#define D_ 2048
#define E_ 300
#define EF4 75              // float4s per embedding row
#define NB 30
#define TILE 128            // doc rows per block (2 per lane)
#define TPB (D_ / TILE)     // tiles per batch = 16

// Hardware-TRANS-pipe transcendentals (R2 post-mortem: ocml tanhf/log1pf left
// drmm_final 99% stalled).
__device__ __forceinline__ float fast_tanh(float x) {
    const float t = __expf(-2.0f * fabsf(x));      // (0,1], never overflows
    const float r = (1.0f - t) / (1.0f + t);
    return copysignf(r, x);
}
__device__ __forceinline__ float fast_log1p(float x) {   // x >= 0 here
    return __logf(1.0f + x);
}

// ---------------- Kernel 1: query prep (qn, gate logits) + hist zero ----------------
__global__ __launch_bounds__(256) void drmm_prep(
    const int* __restrict__ query, const float* __restrict__ emb,
    const float* __restrict__ Wg, const float* __restrict__ bg,
    float* __restrict__ qn, float* __restrict__ gbuf, int* __restrict__ hist)
{
    const int b = blockIdx.x, tid = threadIdx.x;
    const int wid = tid >> 6, lane = tid & 63;

    for (int i = b * 256 + tid; i < B_ * Q_ * NB; i += B_ * 256) hist[i] = 0;

    for (int qq = wid; qq < Q_; qq += 4) {
        const int id = query[b * Q_ + qq];
        const float m = (id > 0) ? 1.f : 0.f;
        const float* row = emb + (long long)((id > 0) ? id : 0) * E_;
        float v[5];
        float ss = 0.f, dg = 0.f;
        #pragma unroll
        for (int k = 0; k < 5; ++k) {
            const int e = lane + 64 * k;
            float x = 0.f, w = 0.f;
            if (e < E_) { x = row[e] * m; w = Wg[e]; }
            v[k] = x;
            ss = fmaf(x, x, ss);
            dg = fmaf(x, w, dg);
        }
        #pragma unroll
        for (int off = 32; off > 0; off >>= 1) {
            ss += __shfl_xor(ss, off);
            dg += __shfl_xor(dg, off);
        }
        // masked row: ss==0 -> rn=inf -> qn = 0*inf = NaN, matching reference 0/0
        const float rn = 1.0f / sqrtf(ss);
        #pragma unroll
        for (int k = 0; k < 5; ++k) {
            const int e = lane + 64 * k;
            if (e < E_) qn[((size_t)(b * Q_ + qq)) * E_ + e] = v[k] * rn;
        }
        if (lane == 0) gbuf[b * Q_ + qq] = fast_tanh(dg + bg[0]);
    }
}

// ---------------- Kernel 2: interaction dots + histogram ----------------
// Block = 128 doc rows, 2 per lane (rA=lane, rB=lane+64); 4 waves split E into
// float4 chunks {19,19,19,18}. Depth-3 ROTATING register pipeline (6 float4
// buffers = 24 VGPR) issues gather loads 3 steps ahead of use: enough MLP to
// lift the gather past 2 TB/s without the R6 disaster (19-deep prefetch = 152
// VGPR -> scratch spill, 10 MB scratch writes, 1.0 TB/s). Each wave-uniform
// ds_read_b128 of q feeds BOTH rows' FMAs (LDS pipe ~12 us/CU).
__global__ __launch_bounds__(256, 2) void drmm_main(
    const int* __restrict__ doc, const float* __restrict__ emb,
    const float* __restrict__ qn, int* __restrict__ hist)
{
    __shared__ __align__(16) float qs[Q_ * E_];      // 19200 B
    __shared__ float part[4][Q_ + 1][TILE];          // 34816 B
    __shared__ int   whist[Q_ * NB];                 // 1920 B

    const int tid = threadIdx.x;
    // XCD-grouped decode: xcd = blk&7 hosts batches {xcd, 8+xcd, 16+xcd, 24+xcd}
    const int blk = blockIdx.x;                      // 0..511
    const int xcd = blk & 7;
    const int j   = blk >> 3;                        // 0..63
    const int b   = ((j & 3) << 3) | xcd;            // 0..31
    const int tile = j >> 2;                         // 0..15
    const int lane = tid & 63, w = tid >> 6;

    // stage qn tile (one coalesced burst) + zero block histogram
    const float4* qb = (const float4*)(qn + (size_t)b * Q_ * E_);
    float4* qs4w = (float4*)qs;
    for (int i = tid; i < Q_ * EF4; i += 256) qs4w[i] = qb[i];
    for (int i = tid; i < Q_ * NB; i += 256) whist[i] = 0;
    __syncthreads();

    const int dbase = b * D_ + tile * TILE + lane;
    const int idA = doc[dbase];
    const int idB = doc[dbase + 64];
    const bool okA = (idA > 0), okB = (idB > 0);
    const int cbeg = w * 19;                 // chunks: 19,19,19,18 float4s
    const bool extra = (w < 3);              // waves 0-2 process a 19th float4
    const float4* rA = ((const float4*)(emb + (long long)(okA ? idA : 0) * E_)) + cbeg;
    const float4* rB = ((const float4*)(emb + (long long)(okB ? idB : 0) * E_)) + cbeg;
    const float4* qs4 = (const float4*)qs;

    float accA[Q_], accB[Q_];
    #pragma unroll
    for (int q = 0; q < Q_; ++q) { accA[q] = 0.f; accB[q] = 0.f; }
    float ssA = 0.f, ssB = 0.f;

    // -------- depth-3 rotating pipeline --------
    float4 a0 = rA[0], b0 = rB[0];
    float4 a1 = rA[1], b1 = rB[1];
    float4 a2 = rA[2], b2 = rB[2];

    #pragma unroll
    for (int k = 0; k < 18; ++k) {
        const float4 a = a0, c = b0;
        a0 = a1; b0 = b1; a1 = a2; b1 = b2;
        const int kn = k + 3;
        if (kn < 18) { a2 = rA[kn]; b2 = rB[kn]; }
        else if (extra && kn < 19) { a2 = rA[kn]; b2 = rB[kn]; }  // wave-uniform
        ssA = fmaf(a.x, a.x, fmaf(a.y, a.y, fmaf(a.z, a.z, fmaf(a.w, a.w, ssA))));
        ssB = fmaf(c.x, c.x, fmaf(c.y, c.y, fmaf(c.z, c.z, fmaf(c.w, c.w, ssB))));
        #pragma unroll
        for (int q = 0; q < Q_; ++q) {
            const float4 u = qs4[q * EF4 + cbeg + k];   // broadcast, feeds 2 rows
            accA[q] = fmaf(a.x, u.x, fmaf(a.y, u.y, fmaf(a.z, u.z, fmaf(a.w, u.w, accA[q]))));
            accB[q] = fmaf(c.x, u.x, fmaf(c.y, u.y, fmaf(c.z, u.z, fmaf(c.w, u.w, accB[q]))));
        }
    }
    if (extra) {                              // k = 18 lives in slot 0 now
        const float4 a = a0, c = b0;
        ssA = fmaf(a.x, a.x, fmaf(a.y, a.y, fmaf(a.z, a.z, fmaf(a.w, a.w, ssA))));
        ssB = fmaf(c.x, c.x, fmaf(c.y, c.y, fmaf(c.z, c.z, fmaf(c.w, c.w, ssB))));
        #pragma unroll
        for (int q = 0; q < Q_; ++q) {
            const float4 u = qs4[q * EF4 + cbeg + 18];
            accA[q] = fmaf(a.x, u.x, fmaf(a.y, u.y, fmaf(a.z, u.z, fmaf(a.w, u.w, accA[q]))));
            accB[q] = fmaf(c.x, u.x, fmaf(c.y, u.y, fmaf(c.z, u.z, fmaf(c.w, u.w, accB[q]))));
        }
    }

    // write partial dots + partial sumsq for both rows
    #pragma unroll
    for (int q = 0; q < Q_; ++q) {
        part[w][q][lane]      = accA[q];
        part[w][q][lane + 64] = accB[q];
    }
    part[w][Q_][lane]      = ssA;
    part[w][Q_][lane + 64] = ssB;
    __syncthreads();

    // combine across waves; thread handles 8 q's for one row
    {
        const int r  = tid & 127;
        const int qh = (tid >> 7) * 8;
        const float sst = part[0][Q_][r] + part[1][Q_][r]
                        + part[2][Q_][r] + part[3][Q_][r];
        const float rn = 1.0f / sqrtf(sst);  // zeros -> inf -> NaN sims -> dropped
        const bool rok = (doc[b * D_ + tile * TILE + r] > 0);
        #pragma unroll
        for (int qq = 0; qq < 8; ++qq) {
            const int q = qh + qq;
            const float s = part[0][q][r] + part[1][q][r]
                          + part[2][q][r] + part[3][q][r];
            const float x = s * rn;          // NaN (masked q row) -> dropped
            const float t = (x + 1.0f) * (NB * 0.5f);
            int bin = (int)floorf(t);
            bin = bin < 0 ? 0 : (bin > NB - 1 ? NB - 1 : bin);
            if (rok && x >= -1.0f && x <= 1.0f)
                atomicAdd(&whist[q * NB + bin], 1);
        }
    }
    __syncthreads();

    // flush block histogram to global
    for (int i = tid; i < Q_ * NB; i += 256) {
        const int v = whist[i];
        if (v) atomicAdd(&hist[b * Q_ * NB + i], v);
    }
}

// ---------------- Kernel 3: log1p + FFN + gated sum ----------------
__global__ __launch_bounds__(64) void drmm_final(
    const int* __restrict__ hist, const float* __restrict__ gbuf,
    const int* __restrict__ query,
    const float* __restrict__ W1, const float* __restrict__ b1,
    const float* __restrict__ W2, const float* __restrict__ b2,
    const float* __restrict__ W3, const float* __restrict__ b3,
    float* __restrict__ out)
{
    const int b = blockIdx.x, lane = threadIdx.x;
    float z = 0.f, e = 0.f;
    if (lane < Q_) {
        const int* h = hist + (b * Q_ + lane) * NB;
        float pre1[5];
        #pragma unroll
        for (int u = 0; u < 5; ++u) pre1[u] = b1[u];
        #pragma unroll
        for (int k = 0; k < NB; ++k) {
            const float hv = fast_log1p((float)h[k]);
            #pragma unroll
            for (int u = 0; u < 5; ++u) pre1[u] = fmaf(hv, W1[k * 5 + u], pre1[u]);
        }
        float z2 = b2[0];
        #pragma unroll
        for (int u = 0; u < 5; ++u) z2 = fmaf(fast_tanh(pre1[u]), W2[u], z2);
        const float z3 = fmaf(fast_tanh(z2), W3[0], b3[0]);
        z = fast_tanh(z3);
        const int id = query[b * Q_ + lane];
        const float g = gbuf[b * Q_ + lane];
        e = (id > 0) ? __expf(g) : 0.f;
    }
    float ze = z * e, se = e;
    #pragma unroll
    for (int off = 32; off > 0; off >>= 1) {
        ze += __shfl_xor(ze, off);
        se += __shfl_xor(se, off);
    }
    if (lane == 0) out[b] = ze / (se + 1e-5f);
}

// ---------------- launch ----------------
extern "C" void kernel_launch(void* const* d_in, const int* in_sizes, int n_in,
                              void* d_out, int out_size, void* d_ws, size_t ws_size,
                              hipStream_t stream)
{
    const int*   query = (const int*)d_in[0];
    const int*   doc   = (const int*)d_in[1];
    // d_in[2] = q_idf (unused by reference)
    const float* emb   = (const float*)d_in[3];
    const float* W1    = (const float*)d_in[4];
    const float* b1    = (const float*)d_in[5];
    const float* W2    = (const float*)d_in[6];
    const float* b2    = (const float*)d_in[7];
    const float* W3    = (const float*)d_in[8];
    const float* b3    = (const float*)d_in[9];
    const float* Wg    = (const float*)d_in[10];
    const float* bg    = (const float*)d_in[11];
    float* out = (float*)d_out;

    // workspace layout
    char* ws = (char*)d_ws;
    float* qn   = (float*)ws;                        // 512*300 f32 = 614400 B
    float* gbuf = (float*)(ws + 614400);             // 512 f32    = 2048 B
    int*   hist = (int*)(ws + 614400 + 2048);        // 15360 ints = 61440 B

    drmm_prep<<<B_, 256, 0, stream>>>(query, emb, Wg, bg, qn, gbuf, hist);
    drmm_main<<<B_ * TPB, 256, 0, stream>>>(doc, emb, qn, hist);
    drmm_final<<<B_, 64, 0, stream>>>(hist, gbuf, query,
                                      W1, b1, W2, b2, W3, b3, out);
}

// Round 8
// 58.789 us; speedup vs baseline: 4.2579x; 4.2579x over previous
//
#include <hip/hip_runtime.h>

#define B_ 32
#define Q_ 16
#define D_ 2048
#define E_ 300
#define EF4 75              // float4s per embedding row
#define NB 30
#define TILE 128            // doc rows per block (2 per lane)
#define TPB (D_ / TILE)     // tiles per batch = 16

// Hardware-TRANS-pipe transcendentals (R2 post-mortem: ocml tanhf/log1pf left
// drmm_final 99% stalled).
__device__ __forceinline__ float fast_tanh(float x) {
    const float t = __expf(-2.0f * fabsf(x));      // (0,1], never overflows
    const float r = (1.0f - t) / (1.0f + t);
    return copysignf(r, x);
}
__device__ __forceinline__ float fast_log1p(float x) {   // x >= 0 here
    return __logf(1.0f + x);
}

// ---------------- Kernel 1: query prep (qn, gate logits) + hist zero ----------------
__global__ __launch_bounds__(256) void drmm_prep(
    const int* __restrict__ query, const float* __restrict__ emb,
    const float* __restrict__ Wg, const float* __restrict__ bg,
    float* __restrict__ qn, float* __restrict__ gbuf, int* __restrict__ hist)
{
    const int b = blockIdx.x, tid = threadIdx.x;
    const int wid = tid >> 6, lane = tid & 63;

    for (int i = b * 256 + tid; i < B_ * Q_ * NB; i += B_ * 256) hist[i] = 0;

    for (int qq = wid; qq < Q_; qq += 4) {
        const int id = query[b * Q_ + qq];
        const float m = (id > 0) ? 1.f : 0.f;
        const float* row = emb + (long long)((id > 0) ? id : 0) * E_;
        float v[5];
        float ss = 0.f, dg = 0.f;
        #pragma unroll
        for (int k = 0; k < 5; ++k) {
            const int e = lane + 64 * k;
            float x = 0.f, w = 0.f;
            if (e < E_) { x = row[e] * m; w = Wg[e]; }
            v[k] = x;
            ss = fmaf(x, x, ss);
            dg = fmaf(x, w, dg);
        }
        #pragma unroll
        for (int off = 32; off > 0; off >>= 1) {
            ss += __shfl_xor(ss, off);
            dg += __shfl_xor(dg, off);
        }
        // masked row: ss==0 -> rn=inf -> qn = 0*inf = NaN, matching reference 0/0
        const float rn = 1.0f / sqrtf(ss);
        #pragma unroll
        for (int k = 0; k < 5; ++k) {
            const int e = lane + 64 * k;
            if (e < E_) qn[((size_t)(b * Q_ + qq)) * E_ + e] = v[k] * rn;
        }
        if (lane == 0) gbuf[b * Q_ + qq] = fast_tanh(dg + bg[0]);
    }
}

// ---------------- Kernel 2: interaction dots + histogram ----------------
// Block = 128 doc rows, 2 per lane (rA=lane, rB=lane+64); 4 waves split E into
// float4 chunks {19,19,19,18}. R7 post-mortem: big unrolled register arrays
// became runtime-indexed when the compiler declined the full unroll -> scratch
// (448 MB spill traffic, 250 us). This version is spill-proof by construction:
// a RUNTIME k-loop (no outer unroll) carrying a depth-2 pipeline in SCALAR
// float4 temps (SSA rotation, 12 VGPR), with only the 16-wide q-loop unrolled
// (static acc indices). Each wave-uniform ds_read_b128 of q feeds both rows.
__global__ __launch_bounds__(256, 4) void drmm_main(
    const int* __restrict__ doc, const float* __restrict__ emb,
    const float* __restrict__ qn, int* __restrict__ hist)
{
    __shared__ __align__(16) float qs[Q_ * E_];      // 19200 B
    __shared__ float part[4][Q_ + 1][TILE];          // 34816 B
    __shared__ int   whist[Q_ * NB];                 // 1920 B

    const int tid = threadIdx.x;
    // XCD-grouped decode: xcd = blk&7 hosts batches {xcd, 8+xcd, 16+xcd, 24+xcd}
    const int blk = blockIdx.x;                      // 0..511
    const int xcd = blk & 7;
    const int j   = blk >> 3;                        // 0..63
    const int b   = ((j & 3) << 3) | xcd;            // 0..31
    const int tile = j >> 2;                         // 0..15
    const int lane = tid & 63, w = tid >> 6;

    // stage qn tile (one coalesced burst) + zero block histogram
    const float4* qb = (const float4*)(qn + (size_t)b * Q_ * E_);
    float4* qs4w = (float4*)qs;
    for (int i = tid; i < Q_ * EF4; i += 256) qs4w[i] = qb[i];
    for (int i = tid; i < Q_ * NB; i += 256) whist[i] = 0;
    __syncthreads();

    const int dbase = b * D_ + tile * TILE + lane;
    const int idA = doc[dbase];
    const int idB = doc[dbase + 64];
    const bool okA = (idA > 0), okB = (idB > 0);
    const int cbeg = w * 19;                 // chunks: 19,19,19,18 float4s
    const int cnt  = (w < 3) ? 19 : 18;
    const float4* rA = ((const float4*)(emb + (long long)(okA ? idA : 0) * E_)) + cbeg;
    const float4* rB = ((const float4*)(emb + (long long)(okB ? idB : 0) * E_)) + cbeg;
    const float4* qs4 = (const float4*)qs + cbeg;

    float accA[Q_], accB[Q_];
    #pragma unroll
    for (int q = 0; q < Q_; ++q) { accA[q] = 0.f; accB[q] = 0.f; }
    float ssA = 0.f, ssB = 0.f;

    // depth-2 pipeline in scalar temps; runtime loop (no outer unroll)
    float4 a0 = rA[0], c0 = rB[0];
    float4 a1 = rA[1], c1 = rB[1];           // cnt >= 18 always
    for (int k = 0; k < cnt; ++k) {
        float4 a2 = a1, c2 = c1;
        const int kn = k + 2;
        if (kn < cnt) { a2 = rA[kn]; c2 = rB[kn]; }   // wave-uniform guard
        const float4 a = a0, c = c0;
        ssA = fmaf(a.x, a.x, fmaf(a.y, a.y, fmaf(a.z, a.z, fmaf(a.w, a.w, ssA))));
        ssB = fmaf(c.x, c.x, fmaf(c.y, c.y, fmaf(c.z, c.z, fmaf(c.w, c.w, ssB))));
        const float4* qk = qs4 + k;
        #pragma unroll
        for (int q = 0; q < Q_; ++q) {
            const float4 u = qk[q * EF4];    // wave-uniform LDS broadcast
            accA[q] = fmaf(a.x, u.x, fmaf(a.y, u.y, fmaf(a.z, u.z, fmaf(a.w, u.w, accA[q]))));
            accB[q] = fmaf(c.x, u.x, fmaf(c.y, u.y, fmaf(c.z, u.z, fmaf(c.w, u.w, accB[q]))));
        }
        a0 = a1; c0 = c1; a1 = a2; c1 = c2;
    }

    // write partial dots + partial sumsq for both rows
    #pragma unroll
    for (int q = 0; q < Q_; ++q) {
        part[w][q][lane]      = accA[q];
        part[w][q][lane + 64] = accB[q];
    }
    part[w][Q_][lane]      = ssA;
    part[w][Q_][lane + 64] = ssB;
    __syncthreads();

    // combine across waves; thread handles 8 q's for one row
    {
        const int r  = tid & 127;
        const int qh = (tid >> 7) * 8;
        const float sst = part[0][Q_][r] + part[1][Q_][r]
                        + part[2][Q_][r] + part[3][Q_][r];
        const float rn = 1.0f / sqrtf(sst);  // zeros -> inf -> NaN sims -> dropped
        const bool rok = (doc[b * D_ + tile * TILE + r] > 0);
        #pragma unroll
        for (int qq = 0; qq < 8; ++qq) {
            const int q = qh + qq;
            const float s = part[0][q][r] + part[1][q][r]
                          + part[2][q][r] + part[3][q][r];
            const float x = s * rn;          // NaN (masked q row) -> dropped
            const float t = (x + 1.0f) * (NB * 0.5f);
            int bin = (int)floorf(t);
            bin = bin < 0 ? 0 : (bin > NB - 1 ? NB - 1 : bin);
            if (rok && x >= -1.0f && x <= 1.0f)
                atomicAdd(&whist[q * NB + bin], 1);
        }
    }
    __syncthreads();

    // flush block histogram to global
    for (int i = tid; i < Q_ * NB; i += 256) {
        const int v = whist[i];
        if (v) atomicAdd(&hist[b * Q_ * NB + i], v);
    }
}

// ---------------- Kernel 3: log1p + FFN + gated sum ----------------
__global__ __launch_bounds__(64) void drmm_final(
    const int* __restrict__ hist, const float* __restrict__ gbuf,
    const int* __restrict__ query,
    const float* __restrict__ W1, const float* __restrict__ b1,
    const float* __restrict__ W2, const float* __restrict__ b2,
    const float* __restrict__ W3, const float* __restrict__ b3,
    float* __restrict__ out)
{
    const int b = blockIdx.x, lane = threadIdx.x;
    float z = 0.f, e = 0.f;
    if (lane < Q_) {
        const int* h = hist + (b * Q_ + lane) * NB;
        float pre1[5];
        #pragma unroll
        for (int u = 0; u < 5; ++u) pre1[u] = b1[u];
        #pragma unroll
        for (int k = 0; k < NB; ++k) {
            const float hv = fast_log1p((float)h[k]);
            #pragma unroll
            for (int u = 0; u < 5; ++u) pre1[u] = fmaf(hv, W1[k * 5 + u], pre1[u]);
        }
        float z2 = b2[0];
        #pragma unroll
        for (int u = 0; u < 5; ++u) z2 = fmaf(fast_tanh(pre1[u]), W2[u], z2);
        const float z3 = fmaf(fast_tanh(z2), W3[0], b3[0]);
        z = fast_tanh(z3);
        const int id = query[b * Q_ + lane];
        const float g = gbuf[b * Q_ + lane];
        e = (id > 0) ? __expf(g) : 0.f;
    }
    float ze = z * e, se = e;
    #pragma unroll
    for (int off = 32; off > 0; off >>= 1) {
        ze += __shfl_xor(ze, off);
        se += __shfl_xor(se, off);
    }
    if (lane == 0) out[b] = ze / (se + 1e-5f);
}

// ---------------- launch ----------------
extern "C" void kernel_launch(void* const* d_in, const int* in_sizes, int n_in,
                              void* d_out, int out_size, void* d_ws, size_t ws_size,
                              hipStream_t stream)
{
    const int*   query = (const int*)d_in[0];
    const int*   doc   = (const int*)d_in[1];
    // d_in[2] = q_idf (unused by reference)
    const float* emb   = (const float*)d_in[3];
    const float* W1    = (const float*)d_in[4];
    const float* b1    = (const float*)d_in[5];
    const float* W2    = (const float*)d_in[6];
    const float* b2    = (const float*)d_in[7];
    const float* W3    = (const float*)d_in[8];
    const float* b3    = (const float*)d_in[9];
    const float* Wg    = (const float*)d_in[10];
    const float* bg    = (const float*)d_in[11];
    float* out = (float*)d_out;

    // workspace layout
    char* ws = (char*)d_ws;
    float* qn   = (float*)ws;                        // 512*300 f32 = 614400 B
    float* gbuf = (float*)(ws + 614400);             // 512 f32    = 2048 B
    int*   hist = (int*)(ws + 614400 + 2048);        // 15360 ints = 61440 B

    drmm_prep<<<B_, 256, 0, stream>>>(query, emb, Wg, bg, qn, gbuf, hist);
    drmm_main<<<B_ * TPB, 256, 0, stream>>>(doc, emb, qn, hist);
    drmm_final<<<B_, 64, 0, stream>>>(hist, gbuf, query,
                                      W1, b1, W2, b2, W3, b3, out);
}